// Round 1
// baseline (146.633 us; speedup 1.0000x reference)
//
#include <hip/hip_runtime.h>
#include <math.h>

#define NN 8192
#define DD 512
#define MM 4
#define EE 131072

// ---------------------------------------------------------------------------
// Kernel 1: reciprocal norms. rn[n][m] = 1 / max(||mh[m] * emb[n]||, 1e-12)
// One block per node n; wave w handles head m=w. Each lane covers 8 d's
// (two float4 chunks at d = lane*4 and d = 256 + lane*4).
// ---------------------------------------------------------------------------
__global__ __launch_bounds__(256) void norm_kernel(const float* __restrict__ emb,
                                                   const float* __restrict__ mh,
                                                   float* __restrict__ rn) {
    const int n    = blockIdx.x;
    const int m    = threadIdx.x >> 6;
    const int lane = threadIdx.x & 63;
    const float* er = emb + (size_t)n * DD;
    const float* mr = mh + (size_t)m * DD;
    const int c0 = lane * 4;
    const int c1 = 256 + lane * 4;

    float4 e0 = *(const float4*)(er + c0);
    float4 e1 = *(const float4*)(er + c1);
    float4 m0 = *(const float4*)(mr + c0);
    float4 m1 = *(const float4*)(mr + c1);

    float ss = 0.f;
    float t;
    t = e0.x * m0.x; ss = fmaf(t, t, ss);
    t = e0.y * m0.y; ss = fmaf(t, t, ss);
    t = e0.z * m0.z; ss = fmaf(t, t, ss);
    t = e0.w * m0.w; ss = fmaf(t, t, ss);
    t = e1.x * m1.x; ss = fmaf(t, t, ss);
    t = e1.y * m1.y; ss = fmaf(t, t, ss);
    t = e1.z * m1.z; ss = fmaf(t, t, ss);
    t = e1.w * m1.w; ss = fmaf(t, t, ss);

    #pragma unroll
    for (int s = 32; s; s >>= 1) ss += __shfl_xor(ss, s, 64);

    if (lane == 0) {
        float nm = fmaxf(sqrtf(ss), 1e-12f);
        rn[(size_t)n * MM + m] = 1.0f / nm;
    }
}

// ---------------------------------------------------------------------------
// Kernel 2: per-edge-pair weighted dot + log terms.
// One wave per pair (grid-stride). Lane covers 8 d's (two float4 chunks).
// w[chunk][dd][m] = mh[m][d]^2 kept in registers (32 VGPRs).
// cos_sum = sum_m acc[m] * rn[i][m] * rn[j][m]
// dist    = (1 + 1e-6) - cos_sum / 4
// term    = pos ? log(dist) : log(1 - dist/2); out += -sum(term)
// ---------------------------------------------------------------------------
__global__ __launch_bounds__(256) void pair_kernel(const int* __restrict__ edges,
                                                   const int* __restrict__ nedges,
                                                   const float* __restrict__ emb,
                                                   const float* __restrict__ mh,
                                                   const float* __restrict__ rn,
                                                   float* __restrict__ out,
                                                   int nblocks) {
    const int lane   = threadIdx.x & 63;
    const int waveId = threadIdx.x >> 6;
    const int gw     = blockIdx.x * 4 + waveId;
    const int nwaves = nblocks * 4;
    const int c0 = lane * 4;
    const int c1 = 256 + lane * 4;

    // Per-lane static weights: w[chunk][dd][m] = mh[m][c+dd]^2
    float w[2][4][4];
    #pragma unroll
    for (int m = 0; m < 4; ++m) {
        float4 w0 = *(const float4*)(mh + (size_t)m * DD + c0);
        float4 w1 = *(const float4*)(mh + (size_t)m * DD + c1);
        w[0][0][m] = w0.x * w0.x; w[0][1][m] = w0.y * w0.y;
        w[0][2][m] = w0.z * w0.z; w[0][3][m] = w0.w * w0.w;
        w[1][0][m] = w1.x * w1.x; w[1][1][m] = w1.y * w1.y;
        w[1][2][m] = w1.z * w1.z; w[1][3][m] = w1.w * w1.w;
    }

    float sum = 0.f;
    const int totalPairs = 2 * EE;

    for (int p = gw; p < totalPairs; p += nwaves) {
        int i, j;
        bool pos = (p < EE);
        if (pos) {
            i = edges[p];
            j = edges[EE + p];
        } else {
            int q = p - EE;
            i = nedges[q];
            j = nedges[EE + q];
        }

        const float* ei = emb + (size_t)i * DD;
        const float* ej = emb + (size_t)j * DD;
        float4 a0 = *(const float4*)(ei + c0);
        float4 b0 = *(const float4*)(ej + c0);
        float4 a1 = *(const float4*)(ei + c1);
        float4 b1 = *(const float4*)(ej + c1);

        float acc0 = 0.f, acc1 = 0.f, acc2 = 0.f, acc3 = 0.f;
        float pr;
        pr = a0.x * b0.x;
        acc0 = fmaf(pr, w[0][0][0], acc0); acc1 = fmaf(pr, w[0][0][1], acc1);
        acc2 = fmaf(pr, w[0][0][2], acc2); acc3 = fmaf(pr, w[0][0][3], acc3);
        pr = a0.y * b0.y;
        acc0 = fmaf(pr, w[0][1][0], acc0); acc1 = fmaf(pr, w[0][1][1], acc1);
        acc2 = fmaf(pr, w[0][1][2], acc2); acc3 = fmaf(pr, w[0][1][3], acc3);
        pr = a0.z * b0.z;
        acc0 = fmaf(pr, w[0][2][0], acc0); acc1 = fmaf(pr, w[0][2][1], acc1);
        acc2 = fmaf(pr, w[0][2][2], acc2); acc3 = fmaf(pr, w[0][2][3], acc3);
        pr = a0.w * b0.w;
        acc0 = fmaf(pr, w[0][3][0], acc0); acc1 = fmaf(pr, w[0][3][1], acc1);
        acc2 = fmaf(pr, w[0][3][2], acc2); acc3 = fmaf(pr, w[0][3][3], acc3);
        pr = a1.x * b1.x;
        acc0 = fmaf(pr, w[1][0][0], acc0); acc1 = fmaf(pr, w[1][0][1], acc1);
        acc2 = fmaf(pr, w[1][0][2], acc2); acc3 = fmaf(pr, w[1][0][3], acc3);
        pr = a1.y * b1.y;
        acc0 = fmaf(pr, w[1][1][0], acc0); acc1 = fmaf(pr, w[1][1][1], acc1);
        acc2 = fmaf(pr, w[1][1][2], acc2); acc3 = fmaf(pr, w[1][1][3], acc3);
        pr = a1.z * b1.z;
        acc0 = fmaf(pr, w[1][2][0], acc0); acc1 = fmaf(pr, w[1][2][1], acc1);
        acc2 = fmaf(pr, w[1][2][2], acc2); acc3 = fmaf(pr, w[1][2][3], acc3);
        pr = a1.w * b1.w;
        acc0 = fmaf(pr, w[1][3][0], acc0); acc1 = fmaf(pr, w[1][3][1], acc1);
        acc2 = fmaf(pr, w[1][3][2], acc2); acc3 = fmaf(pr, w[1][3][3], acc3);

        #pragma unroll
        for (int s = 32; s; s >>= 1) {
            acc0 += __shfl_xor(acc0, s, 64);
            acc1 += __shfl_xor(acc1, s, 64);
            acc2 += __shfl_xor(acc2, s, 64);
            acc3 += __shfl_xor(acc3, s, 64);
        }

        float4 ri = *(const float4*)(rn + (size_t)i * MM);
        float4 rj = *(const float4*)(rn + (size_t)j * MM);
        float cs = acc0 * ri.x * rj.x + acc1 * ri.y * rj.y +
                   acc2 * ri.z * rj.z + acc3 * ri.w * rj.w;
        float dist = (1.0f + 1e-6f) - 0.25f * cs;
        float term = pos ? logf(dist) : logf(1.0f - 0.5f * dist);
        sum += term;
    }

    __shared__ float wsum[4];
    if (lane == 0) wsum[waveId] = sum;
    __syncthreads();
    if (threadIdx.x == 0) {
        float t = wsum[0] + wsum[1] + wsum[2] + wsum[3];
        atomicAdd(out, -t);
    }
}

extern "C" void kernel_launch(void* const* d_in, const int* in_sizes, int n_in,
                              void* d_out, int out_size, void* d_ws, size_t ws_size,
                              hipStream_t stream) {
    const int*   edges  = (const int*)d_in[0];
    const int*   nedges = (const int*)d_in[1];
    const float* emb    = (const float*)d_in[2];
    const float* mh     = (const float*)d_in[3];
    float* out = (float*)d_out;
    float* rn  = (float*)d_ws;   // N*M floats = 128 KiB

    hipMemsetAsync(d_out, 0, (size_t)out_size * sizeof(float), stream);
    norm_kernel<<<NN, 256, 0, stream>>>(emb, mh, rn);

    const int nblocks = 4096;
    pair_kernel<<<nblocks, 256, 0, stream>>>(edges, nedges, emb, mh, rn, out, nblocks);
}

// Round 2
// 99.894 us; speedup vs baseline: 1.4679x; 1.4679x over previous
//
#include <hip/hip_runtime.h>
#include <math.h>

#define NN 8192
#define DD 512
#define MM 4
#define EE 131072

typedef float floatx2 __attribute__((ext_vector_type(2)));

__device__ inline void unpack8(uint2 u, float* f) {
    floatx2 p;
    p = __builtin_amdgcn_cvt_pk_f32_fp8((int)u.x, false); f[0] = p[0]; f[1] = p[1];
    p = __builtin_amdgcn_cvt_pk_f32_fp8((int)u.x, true);  f[2] = p[0]; f[3] = p[1];
    p = __builtin_amdgcn_cvt_pk_f32_fp8((int)u.y, false); f[4] = p[0]; f[5] = p[1];
    p = __builtin_amdgcn_cvt_pk_f32_fp8((int)u.y, true);  f[6] = p[0]; f[7] = p[1];
}

// ---------------------------------------------------------------------------
// Kernel 1: quantize emb rows to fp8 e4m3 AND compute reciprocal norms from
// the DEQUANTIZED values (self-consistency => cos(i,i) == 1 exactly).
// One block per node; wave m handles head m; lane covers d = lane*8 .. +7.
// ---------------------------------------------------------------------------
__global__ __launch_bounds__(256) void quant_norm_kernel(const float* __restrict__ emb,
                                                         const float* __restrict__ mh,
                                                         uint2* __restrict__ q,
                                                         float* __restrict__ rn) {
    const int n    = blockIdx.x;
    const int m    = threadIdx.x >> 6;
    const int lane = threadIdx.x & 63;

    const float* er = emb + (size_t)n * DD + lane * 8;
    float4 e0 = *(const float4*)(er);
    float4 e1 = *(const float4*)(er + 4);

    int lo = 0, hi = 0;
    lo = __builtin_amdgcn_cvt_pk_fp8_f32(e0.x, e0.y, lo, false);
    lo = __builtin_amdgcn_cvt_pk_fp8_f32(e0.z, e0.w, lo, true);
    hi = __builtin_amdgcn_cvt_pk_fp8_f32(e1.x, e1.y, hi, false);
    hi = __builtin_amdgcn_cvt_pk_fp8_f32(e1.z, e1.w, hi, true);

    if (m == 0) q[(size_t)n * 64 + lane] = make_uint2((unsigned)lo, (unsigned)hi);

    float qv[8];
    unpack8(make_uint2((unsigned)lo, (unsigned)hi), qv);

    const float* mr = mh + (size_t)m * DD + lane * 8;
    float4 m0 = *(const float4*)(mr);
    float4 m1 = *(const float4*)(mr + 4);

    float ss = 0.f, t;
    t = qv[0] * m0.x; ss = fmaf(t, t, ss);
    t = qv[1] * m0.y; ss = fmaf(t, t, ss);
    t = qv[2] * m0.z; ss = fmaf(t, t, ss);
    t = qv[3] * m0.w; ss = fmaf(t, t, ss);
    t = qv[4] * m1.x; ss = fmaf(t, t, ss);
    t = qv[5] * m1.y; ss = fmaf(t, t, ss);
    t = qv[6] * m1.z; ss = fmaf(t, t, ss);
    t = qv[7] * m1.w; ss = fmaf(t, t, ss);

    #pragma unroll
    for (int s = 32; s; s >>= 1) ss += __shfl_xor(ss, s, 64);

    if (lane == 0) {
        rn[(size_t)n * MM + m] = 1.0f / fmaxf(sqrtf(ss), 1e-12f);
    }
}

// ---------------------------------------------------------------------------
// Kernel 2: per-pair weighted dot on fp8 rows.
// One wave per pair (grid-stride); lane covers d = lane*8 .. +7 (uint2 = 8 B).
// rn product folded per-lane BEFORE the single butterfly reduction.
// ---------------------------------------------------------------------------
__global__ __launch_bounds__(256) void pair_kernel(const int* __restrict__ edges,
                                                   const int* __restrict__ nedges,
                                                   const uint2* __restrict__ q,
                                                   const float* __restrict__ mh,
                                                   const float* __restrict__ rn,
                                                   float* __restrict__ out,
                                                   int nblocks) {
    const int lane   = threadIdx.x & 63;
    const int waveId = threadIdx.x >> 6;
    const int gw     = blockIdx.x * 4 + waveId;
    const int nwaves = nblocks * 4;

    // Per-lane static weights: w[m][dd] = mh[m][lane*8+dd]^2  (32 VGPRs)
    const float* mbase = mh + lane * 8;
    float w[4][8];
    #pragma unroll
    for (int m = 0; m < 4; ++m) {
        float4 w0 = *(const float4*)(mbase + (size_t)m * DD);
        float4 w1 = *(const float4*)(mbase + (size_t)m * DD + 4);
        w[m][0] = w0.x * w0.x; w[m][1] = w0.y * w0.y;
        w[m][2] = w0.z * w0.z; w[m][3] = w0.w * w0.w;
        w[m][4] = w1.x * w1.x; w[m][5] = w1.y * w1.y;
        w[m][6] = w1.z * w1.z; w[m][7] = w1.w * w1.w;
    }

    float sum = 0.f;
    const int totalPairs = 2 * EE;

    for (int p = gw; p < totalPairs; p += nwaves) {
        const bool pos = (p < EE);
        const int* eb = pos ? edges : nedges;
        const int pp  = pos ? p : p - EE;
        const int i = eb[pp];
        const int j = eb[EE + pp];

        uint2 qa = q[(size_t)i * 64 + lane];
        uint2 qb = q[(size_t)j * 64 + lane];

        float a[8], b[8];
        unpack8(qa, a);
        unpack8(qb, b);

        float acc0 = 0.f, acc1 = 0.f, acc2 = 0.f, acc3 = 0.f;
        #pragma unroll
        for (int dd = 0; dd < 8; ++dd) {
            float pr = a[dd] * b[dd];
            acc0 = fmaf(pr, w[0][dd], acc0);
            acc1 = fmaf(pr, w[1][dd], acc1);
            acc2 = fmaf(pr, w[2][dd], acc2);
            acc3 = fmaf(pr, w[3][dd], acc3);
        }

        float4 ri = *(const float4*)(rn + (size_t)i * MM);
        float4 rj = *(const float4*)(rn + (size_t)j * MM);
        float v = acc0 * (ri.x * rj.x) + acc1 * (ri.y * rj.y) +
                  acc2 * (ri.z * rj.z) + acc3 * (ri.w * rj.w);

        #pragma unroll
        for (int s = 32; s; s >>= 1) v += __shfl_xor(v, s, 64);

        float dist = 1.000001f - 0.25f * v;
        float arg  = pos ? dist : fmaf(-0.5f, dist, 1.0f);
        sum += __logf(fmaxf(arg, 1e-8f));
    }

    __shared__ float wsum[4];
    if (lane == 0) wsum[waveId] = sum;
    __syncthreads();
    if (threadIdx.x == 0) {
        float t = wsum[0] + wsum[1] + wsum[2] + wsum[3];
        atomicAdd(out, -t);
    }
}

extern "C" void kernel_launch(void* const* d_in, const int* in_sizes, int n_in,
                              void* d_out, int out_size, void* d_ws, size_t ws_size,
                              hipStream_t stream) {
    const int*   edges  = (const int*)d_in[0];
    const int*   nedges = (const int*)d_in[1];
    const float* emb    = (const float*)d_in[2];
    const float* mh     = (const float*)d_in[3];
    float* out = (float*)d_out;

    uint2* q  = (uint2*)d_ws;                                   // 8192*512 B = 4 MiB
    float* rn = (float*)((char*)d_ws + (size_t)NN * DD);        // 128 KiB

    hipMemsetAsync(d_out, 0, (size_t)out_size * sizeof(float), stream);
    quant_norm_kernel<<<NN, 256, 0, stream>>>(emb, mh, q, rn);

    const int nblocks = 4096;
    pair_kernel<<<nblocks, 256, 0, stream>>>(edges, nedges, q, mh, rn, out, nblocks);
}

// Round 3
// 82.028 us; speedup vs baseline: 1.7876x; 1.2178x over previous
//
#include <hip/hip_runtime.h>
#include <math.h>

#define NN 8192
#define DD 512
#define MM 4
#define EE 131072

typedef float floatx2 __attribute__((ext_vector_type(2)));

__device__ inline void unpack8(uint2 u, float* f) {
    floatx2 p;
    p = __builtin_amdgcn_cvt_pk_f32_fp8((int)u.x, false); f[0] = p[0]; f[1] = p[1];
    p = __builtin_amdgcn_cvt_pk_f32_fp8((int)u.x, true);  f[2] = p[0]; f[3] = p[1];
    p = __builtin_amdgcn_cvt_pk_f32_fp8((int)u.y, false); f[4] = p[0]; f[5] = p[1];
    p = __builtin_amdgcn_cvt_pk_f32_fp8((int)u.y, true);  f[6] = p[0]; f[7] = p[1];
}

// ---------------------------------------------------------------------------
// Kernel 1: quantize emb rows to fp8 e4m3 AND compute reciprocal norms from
// the DEQUANTIZED values. One WAVE per node (all 4 heads); lane covers
// d = lane*8..+7. Batched 4-value butterfly; lane 0 stores rn[n] as float4.
// ---------------------------------------------------------------------------
__global__ __launch_bounds__(256) void quant_norm_kernel(const float* __restrict__ emb,
                                                         const float* __restrict__ mh,
                                                         uint2* __restrict__ q,
                                                         float* __restrict__ rn) {
    const int lane = threadIdx.x & 63;
    const int n    = blockIdx.x * 4 + (threadIdx.x >> 6);

    const float* er = emb + (size_t)n * DD + lane * 8;
    float4 e0 = *(const float4*)(er);
    float4 e1 = *(const float4*)(er + 4);

    int lo = 0, hi = 0;
    lo = __builtin_amdgcn_cvt_pk_fp8_f32(e0.x, e0.y, lo, false);
    lo = __builtin_amdgcn_cvt_pk_fp8_f32(e0.z, e0.w, lo, true);
    hi = __builtin_amdgcn_cvt_pk_fp8_f32(e1.x, e1.y, hi, false);
    hi = __builtin_amdgcn_cvt_pk_fp8_f32(e1.z, e1.w, hi, true);

    q[(size_t)n * 64 + lane] = make_uint2((unsigned)lo, (unsigned)hi);

    float qv[8];
    unpack8(make_uint2((unsigned)lo, (unsigned)hi), qv);

    const float* mbase = mh + lane * 8;
    float ss[4];
    #pragma unroll
    for (int m = 0; m < 4; ++m) {
        float4 m0 = *(const float4*)(mbase + (size_t)m * DD);
        float4 m1 = *(const float4*)(mbase + (size_t)m * DD + 4);
        float s = 0.f, t;
        t = qv[0] * m0.x; s = fmaf(t, t, s);
        t = qv[1] * m0.y; s = fmaf(t, t, s);
        t = qv[2] * m0.z; s = fmaf(t, t, s);
        t = qv[3] * m0.w; s = fmaf(t, t, s);
        t = qv[4] * m1.x; s = fmaf(t, t, s);
        t = qv[5] * m1.y; s = fmaf(t, t, s);
        t = qv[6] * m1.z; s = fmaf(t, t, s);
        t = qv[7] * m1.w; s = fmaf(t, t, s);
        ss[m] = s;
    }

    #pragma unroll
    for (int s = 32; s; s >>= 1) {
        ss[0] += __shfl_xor(ss[0], s, 64);
        ss[1] += __shfl_xor(ss[1], s, 64);
        ss[2] += __shfl_xor(ss[2], s, 64);
        ss[3] += __shfl_xor(ss[3], s, 64);
    }

    if (lane == 0) {
        float4 r;
        r.x = 1.0f / fmaxf(sqrtf(ss[0]), 1e-12f);
        r.y = 1.0f / fmaxf(sqrtf(ss[1]), 1e-12f);
        r.z = 1.0f / fmaxf(sqrtf(ss[2]), 1e-12f);
        r.w = 1.0f / fmaxf(sqrtf(ss[3]), 1e-12f);
        *(float4*)(rn + (size_t)n * MM) = r;
    }
}

// ---------------------------------------------------------------------------
// Kernel 2: per-pair weighted dot on fp8 rows, 4 pairs per macro-iteration.
// Wave owns 16 CONTIGUOUS pairs (so pos/neg is wave-uniform and index loads
// are two int4's per macro-iter). All 16 loads of a macro-iter issue before
// any compute; one batched 6-round butterfly reduces 4 pairs at once.
// ---------------------------------------------------------------------------
__device__ inline float pair_dot(uint2 qa, uint2 qb, const float w[4][8],
                                 float4 ri, float4 rj) {
    float a[8], b[8];
    unpack8(qa, a);
    unpack8(qb, b);
    float acc0 = 0.f, acc1 = 0.f, acc2 = 0.f, acc3 = 0.f;
    #pragma unroll
    for (int dd = 0; dd < 8; ++dd) {
        float pr = a[dd] * b[dd];
        acc0 = fmaf(pr, w[0][dd], acc0);
        acc1 = fmaf(pr, w[1][dd], acc1);
        acc2 = fmaf(pr, w[2][dd], acc2);
        acc3 = fmaf(pr, w[3][dd], acc3);
    }
    float v = acc0 * (ri.x * rj.x);
    v = fmaf(acc1, ri.y * rj.y, v);
    v = fmaf(acc2, ri.z * rj.z, v);
    v = fmaf(acc3, ri.w * rj.w, v);
    return v;
}

__global__ __launch_bounds__(256) void pair_kernel(const int* __restrict__ edges,
                                                   const int* __restrict__ nedges,
                                                   const uint2* __restrict__ q,
                                                   const float* __restrict__ mh,
                                                   const float* __restrict__ rn,
                                                   float* __restrict__ out) {
    const int lane   = threadIdx.x & 63;
    const int waveId = threadIdx.x >> 6;
    const int gw     = blockIdx.x * 4 + waveId;   // 16384 waves

    // Per-lane static weights: w[m][dd] = mh[m][lane*8+dd]^2  (32 VGPRs)
    const float* mbase = mh + lane * 8;
    float w[4][8];
    #pragma unroll
    for (int m = 0; m < 4; ++m) {
        float4 w0 = *(const float4*)(mbase + (size_t)m * DD);
        float4 w1 = *(const float4*)(mbase + (size_t)m * DD + 4);
        w[m][0] = w0.x * w0.x; w[m][1] = w0.y * w0.y;
        w[m][2] = w0.z * w0.z; w[m][3] = w0.w * w0.w;
        w[m][4] = w1.x * w1.x; w[m][5] = w1.y * w1.y;
        w[m][6] = w1.z * w1.z; w[m][7] = w1.w * w1.w;
    }

    const int  base = gw * 16;              // 16 pairs per wave, contiguous
    const bool pos  = (base < EE);
    const int* eb   = pos ? edges : nedges;
    const int  lb   = pos ? base : base - EE;

    float sum = 0.f;

    #pragma unroll 1
    for (int t = 0; t < 4; ++t) {
        const int pb = lb + t * 4;
        int4 iv = *(const int4*)(eb + pb);
        int4 jv = *(const int4*)(eb + EE + pb);

        // issue all 8 row gathers + 8 rn gathers
        uint2 qa0 = q[(size_t)iv.x * 64 + lane];
        uint2 qb0 = q[(size_t)jv.x * 64 + lane];
        uint2 qa1 = q[(size_t)iv.y * 64 + lane];
        uint2 qb1 = q[(size_t)jv.y * 64 + lane];
        uint2 qa2 = q[(size_t)iv.z * 64 + lane];
        uint2 qb2 = q[(size_t)jv.z * 64 + lane];
        uint2 qa3 = q[(size_t)iv.w * 64 + lane];
        uint2 qb3 = q[(size_t)jv.w * 64 + lane];
        float4 ri0 = *(const float4*)(rn + (size_t)iv.x * MM);
        float4 rj0 = *(const float4*)(rn + (size_t)jv.x * MM);
        float4 ri1 = *(const float4*)(rn + (size_t)iv.y * MM);
        float4 rj1 = *(const float4*)(rn + (size_t)jv.y * MM);
        float4 ri2 = *(const float4*)(rn + (size_t)iv.z * MM);
        float4 rj2 = *(const float4*)(rn + (size_t)jv.z * MM);
        float4 ri3 = *(const float4*)(rn + (size_t)iv.w * MM);
        float4 rj3 = *(const float4*)(rn + (size_t)jv.w * MM);

        float v0 = pair_dot(qa0, qb0, w, ri0, rj0);
        float v1 = pair_dot(qa1, qb1, w, ri1, rj1);
        float v2 = pair_dot(qa2, qb2, w, ri2, rj2);
        float v3 = pair_dot(qa3, qb3, w, ri3, rj3);

        // batched butterfly: 6 rounds x 4 independent values
        #pragma unroll
        for (int s = 32; s; s >>= 1) {
            v0 += __shfl_xor(v0, s, 64);
            v1 += __shfl_xor(v1, s, 64);
            v2 += __shfl_xor(v2, s, 64);
            v3 += __shfl_xor(v3, s, 64);
        }

        float d0 = 1.000001f - 0.25f * v0;
        float d1 = 1.000001f - 0.25f * v1;
        float d2 = 1.000001f - 0.25f * v2;
        float d3 = 1.000001f - 0.25f * v3;
        float a0 = pos ? d0 : fmaf(-0.5f, d0, 1.0f);
        float a1 = pos ? d1 : fmaf(-0.5f, d1, 1.0f);
        float a2 = pos ? d2 : fmaf(-0.5f, d2, 1.0f);
        float a3 = pos ? d3 : fmaf(-0.5f, d3, 1.0f);
        sum += __logf(fmaxf(a0, 1e-8f)) + __logf(fmaxf(a1, 1e-8f)) +
               __logf(fmaxf(a2, 1e-8f)) + __logf(fmaxf(a3, 1e-8f));
    }

    __shared__ float wsum[4];
    if (lane == 0) wsum[waveId] = sum;
    __syncthreads();
    if (threadIdx.x == 0) {
        float t = wsum[0] + wsum[1] + wsum[2] + wsum[3];
        atomicAdd(out, -t);
    }
}

extern "C" void kernel_launch(void* const* d_in, const int* in_sizes, int n_in,
                              void* d_out, int out_size, void* d_ws, size_t ws_size,
                              hipStream_t stream) {
    const int*   edges  = (const int*)d_in[0];
    const int*   nedges = (const int*)d_in[1];
    const float* emb    = (const float*)d_in[2];
    const float* mh     = (const float*)d_in[3];
    float* out = (float*)d_out;

    uint2* q  = (uint2*)d_ws;                                   // 4 MiB
    float* rn = (float*)((char*)d_ws + (size_t)NN * DD);        // 128 KiB

    hipMemsetAsync(d_out, 0, (size_t)out_size * sizeof(float), stream);
    quant_norm_kernel<<<NN / 4, 256, 0, stream>>>(emb, mh, q, rn);
    pair_kernel<<<4096, 256, 0, stream>>>(edges, nedges, q, mh, rn, out);
}